// Round 2
// baseline (616.611 us; speedup 1.0000x reference)
//
#include <hip/hip_runtime.h>
#include <cstdint>
#include <cstddef>

#define N_NODES 200000
#define N_EDGES 6400000
#define NB      64
#define MROWS   8192     // NB*ROWS
#define FEAT    2560

// edge bucketing: bucket = 256 consecutive dst nodes
#define BSZ   256
#define NBK   782        // ceil(200000/256)
#define EBLK  1024       // edge_bucket blocks
#define ETILE 6250       // edges per block (EBLK*ETILE == N_EDGES)
#define BCAP  8960       // per-bucket region capacity (mean 8187, sd ~90)

typedef __attribute__((ext_vector_type(8))) short bf16x8;
typedef __attribute__((ext_vector_type(4))) float f32x4;

__device__ __forceinline__ unsigned short bf16rne(float f) {
    unsigned u = __builtin_bit_cast(unsigned, f);
    u += 0x7fffu + ((u >> 16) & 1u);
    return (unsigned short)(u >> 16);
}

__device__ __forceinline__ void async_cp16(const void* g, void* l) {
    __builtin_amdgcn_global_load_lds(
        (const __attribute__((address_space(1))) unsigned int*)g,
        (__attribute__((address_space(3))) unsigned int*)l, 16, 0, 0);
}

// unpack bf16x6 gather, accumulate one edge into register z/agg
__device__ __forceinline__ void edge_acc(
    uint4 g, const float* xrd, const float* attv, float& z, float* agg)
{
    float xls[6];
    xls[0] = __builtin_bit_cast(float, g.x << 16);
    xls[1] = __builtin_bit_cast(float, g.x & 0xffff0000u);
    xls[2] = __builtin_bit_cast(float, g.y << 16);
    xls[3] = __builtin_bit_cast(float, g.y & 0xffff0000u);
    xls[4] = __builtin_bit_cast(float, g.z << 16);
    xls[5] = __builtin_bit_cast(float, g.z & 0xffff0000u);
    float sc = 0.f;
#pragma unroll
    for (int j = 0; j < 6; j++) {
        float e = xls[j] + xrd[j];
        e = (e >= 0.f) ? e : 0.2f * e;
        sc += attv[j] * e;
    }
    const float p = __expf(sc);
    z += p;
#pragma unroll
    for (int j = 0; j < 6; j++) agg[j] += p * xls[j];
}

// ---------------------------------------------------------------------------
// Workspace layout (4-byte units), edge scratch aliased over MLP scratch:
//   xlb  (bf16[200000][8])   @ 0
//   xr   (f32 [200000][8])   @ 800,000
//   w1t  (bf16[256][2560])   @ 2,400,000
//   w2t  (bf16[64][256])     @ 2,727,680
//   gsum [256] @2,735,872 ; gcnt [64] @2,736,128 ; cursor [782] @2,736,192
//     (memset span: 1102 dw from gsum)
//   union @ 2,737,024:
//     edge: pairs[782*8960] .. 9,743,744   (39.0 MB total)
//     mlp:  f1 f32[8192*256] @2,737,024; f1b bf16 @4,834,176;
//           f2 @5,358,464; f3 @5,882,752
// ---------------------------------------------------------------------------

// xl (bf16 packed, 16B/node) and xr (f32, stride 8) node transforms.
__global__ __launch_bounds__(256) void node_xform(
    const float* __restrict__ x,
    const float* __restrict__ Wl, const float* __restrict__ bl,
    const float* __restrict__ Wr, const float* __restrict__ br,
    unsigned short* __restrict__ xlb, float* __restrict__ xr)
{
    const int t = threadIdx.x;
    const int l = t & 15;
    const int node = blockIdx.x * 16 + (t >> 4);

    float wl[48], wr[48];
#pragma unroll
    for (int q = 0; q < 12; q++) {
        *(float4*)&wl[q * 4] = *(const float4*)(Wl + 48 * l + 4 * q);
        *(float4*)&wr[q * 4] = *(const float4*)(Wr + 48 * l + 4 * q);
    }
    float xv[8];
    *(float4*)&xv[0] = *(const float4*)(x + (size_t)node * 128 + l * 8);
    *(float4*)&xv[4] = *(const float4*)(x + (size_t)node * 128 + l * 8 + 4);

    float al[6] = {}, ar[6] = {};
#pragma unroll
    for (int i = 0; i < 8; i++) {
#pragma unroll
        for (int j = 0; j < 6; j++) {
            al[j] += xv[i] * wl[i * 6 + j];
            ar[j] += xv[i] * wr[i * 6 + j];
        }
    }
#pragma unroll
    for (int off = 8; off >= 1; off >>= 1) {
#pragma unroll
        for (int j = 0; j < 6; j++) {
            al[j] += __shfl_xor(al[j], off);
            ar[j] += __shfl_xor(ar[j], off);
        }
    }
    if (l == 0) {
        union { unsigned short h[8]; uint4 v; } u;
#pragma unroll
        for (int j = 0; j < 6; j++) u.h[j] = bf16rne(al[j] + bl[j]);
        u.h[6] = 0; u.h[7] = 0;
        *(uint4*)(xlb + (size_t)node * 8) = u.v;
        float4 r0; float2 r1;
        r0.x = ar[0] + br[0]; r0.y = ar[1] + br[1];
        r0.z = ar[2] + br[2]; r0.w = ar[3] + br[3];
        r1.x = ar[4] + br[4]; r1.y = ar[5] + br[5];
        *(float4*)(xr + (size_t)node * 8) = r0;
        *(float2*)(xr + (size_t)node * 8 + 4) = r1;
    }
}

// LDS counting-sort bucketizer. Pass 1 histograms dst buckets; block-wide
// prefix scan gives per-bucket chunk offsets; global spans are reserved with
// one atomicAdd per (block,bucket) ISSUED BEFORE pass 2 (latency hidden);
// pass 2 scatters pairs into LDS sorted-by-bucket; copy-out writes each
// bucket's contiguous run to its reserved span with an 8-lane group (avg
// span = 8 entries = 32B). No per-edge global scatter.
// ETILE=6250 keeps LDS ~34.4KB -> 4 blocks/CU (16 waves) for latency hiding.
// pairs = src<<8 | dst&255.
__global__ __launch_bounds__(256) void edge_bucket(
    const int* __restrict__ ei, int* __restrict__ cursor, int* __restrict__ pairs)
{
    __shared__ int sorted[ETILE];      // chunk sorted by bucket
    __shared__ int hb[NBK + 1];        // exclusive bucket starts (+ total)
    __shared__ int cur[NBK];           // hist, then scatter cursor
    __shared__ int gbl[NBK];           // reserved global span base
    __shared__ int wsum[4];
    const int t = threadIdx.x;
    const int lane = t & 63, wid = t >> 6;
    const int base = blockIdx.x * ETILE;

    for (int b = t; b < NBK; b += 256) cur[b] = 0;
    __syncthreads();

    // pass 1: histogram dst buckets (dst re-read in pass 2 from L2)
    for (int i = t; i < ETILE; i += 256)
        atomicAdd(&cur[ei[N_EDGES + base + i] >> 8], 1);
    __syncthreads();

    // block-wide exclusive prefix: thread t owns buckets 4t..4t+3
    int c[4]; int lsum = 0;
#pragma unroll
    for (int q = 0; q < 4; q++) {
        const int b = 4 * t + q;
        c[q] = (b < NBK) ? cur[b] : 0;
        lsum += c[q];
    }
    int v = lsum;
#pragma unroll
    for (int d = 1; d < 64; d <<= 1) {
        const int o = __shfl_up(v, d);
        if (lane >= d) v += o;
    }
    if (lane == 63) wsum[wid] = v;
    __syncthreads();                    // also orders cur[] reads vs rewrite
    int off = 0;
#pragma unroll
    for (int w = 0; w < 3; w++) if (w < wid) off += wsum[w];
    int run = off + v - lsum;           // exclusive start for bucket 4t

    // reserve global spans now; results consumed after pass 2
    int mygb[4];
#pragma unroll
    for (int q = 0; q < 4; q++) {
        const int b = 4 * t + q;
        mygb[q] = (b < NBK && c[q] > 0) ? atomicAdd(&cursor[b], c[q]) : 0;
    }

#pragma unroll
    for (int q = 0; q < 4; q++) {
        const int b = 4 * t + q;
        if (b <= NBK) hb[b] = run;      // hb[NBK] = ETILE total
        if (b < NBK) cur[b] = run;      // becomes scatter cursor
        run += c[q];
    }
    __syncthreads();

    // pass 2: LDS counting-sort scatter (pure LDS per edge)
    for (int i = t; i < ETILE; i += 256) {
        const int d = ei[N_EDGES + base + i];
        const int s = ei[base + i];
        const int pos = atomicAdd(&cur[d >> 8], 1);
        sorted[pos] = (s << 8) | (d & 255);
    }
#pragma unroll
    for (int q = 0; q < 4; q++) {
        const int b = 4 * t + q;
        if (b < NBK) gbl[b] = mygb[q];  // waits on atomics here (hidden)
    }
    __syncthreads();

    // copy-out: 8-lane group per bucket -> contiguous span writes
    const int grp = t >> 3, gl = t & 7;
    for (int b = grp; b < NBK; b += 32) {
        const int st = hb[b];
        const int cnt = hb[b + 1] - st;
        int* dst = pairs + b * BCAP + gbl[b];
        for (int i = gl; i < cnt; i += 8)
            dst[i] = sorted[st + i];
    }
}

// One block per 256-node bucket. In-LDS counting sort by local dst, then
// thread t owns dst t: walks its contiguous run, accumulates in registers.
// Fused finalize + jk + pooled segment-mean.
__global__ __launch_bounds__(256) void bucket_reduce(
    const int* __restrict__ pairs, const int* __restrict__ cursor,
    const unsigned short* __restrict__ xlb, const float* __restrict__ xr,
    const float* __restrict__ att, const float* __restrict__ conv_b,
    const float* __restrict__ jkW, const float* __restrict__ jkb,
    const int* __restrict__ batch,
    float* __restrict__ gsum, float* __restrict__ gcnt)
{
    __shared__ int sorted[BCAP];
    __shared__ int hist[256];     // histogram, then scatter cursor
    __shared__ int wtot[4];
    const int t = threadIdx.x;
    const int lane = t & 63, wid = t >> 6;
    const int d0 = blockIdx.x * BSZ + t;

    float xrd[6];
    if (d0 < N_NODES) {
        float4 a = *(const float4*)(xr + (size_t)d0 * 8);
        float2 b = *(const float2*)(xr + (size_t)d0 * 8 + 4);
        xrd[0] = a.x; xrd[1] = a.y; xrd[2] = a.z;
        xrd[3] = a.w; xrd[4] = b.x; xrd[5] = b.y;
    } else {
#pragma unroll
        for (int j = 0; j < 6; j++) xrd[j] = 0.f;
    }
    float attv[6];
#pragma unroll
    for (int j = 0; j < 6; j++) attv[j] = att[j];

    float z = 0.f, agg[6] = {};
    const uint4* xl4 = (const uint4*)xlb;
    const int e0 = blockIdx.x * BCAP;
    const int e1 = e0 + cursor[blockIdx.x];

    for (int c0 = e0; c0 < e1; c0 += BCAP) {
        const int rem = e1 - c0;
        const int cnt_chunk = (rem < BCAP) ? rem : BCAP;
        hist[t] = 0;
        __syncthreads();
        for (int i = t; i < cnt_chunk; i += 256)
            atomicAdd(&hist[pairs[c0 + i] & 255], 1);
        __syncthreads();
        // exclusive prefix: wave shfl-scan + cross-wave offsets
        const int h = hist[t];
        int v = h;
#pragma unroll
        for (int d = 1; d < 64; d <<= 1) {
            int o = __shfl_up(v, d);
            if (lane >= d) v += o;
        }
        if (lane == 63) wtot[wid] = v;
        __syncthreads();
        int off = 0;
#pragma unroll
        for (int wv = 0; wv < 3; wv++) if (wv < wid) off += wtot[wv];
        const int my_start = v - h + off;
        const int my_cnt = h;
        __syncthreads();
        hist[t] = my_start;        // becomes scatter cursor
        __syncthreads();
        for (int i = t; i < cnt_chunk; i += 256) {
            const int pv = pairs[c0 + i];
            const int pos = atomicAdd(&hist[pv & 255], 1);
            sorted[pos] = ((unsigned)pv) >> 8;
        }
        __syncthreads();
        // walk my run: 4-wide batched gathers (independent -> pipelined)
        int i = 0;
        for (; i + 4 <= my_cnt; i += 4) {
            const int s0 = sorted[my_start + i];
            const int s1 = sorted[my_start + i + 1];
            const int s2 = sorted[my_start + i + 2];
            const int s3 = sorted[my_start + i + 3];
            const uint4 g0 = xl4[s0], g1 = xl4[s1], g2 = xl4[s2], g3 = xl4[s3];
            edge_acc(g0, xrd, attv, z, agg);
            edge_acc(g1, xrd, attv, z, agg);
            edge_acc(g2, xrd, attv, z, agg);
            edge_acc(g3, xrd, attv, z, agg);
        }
        for (; i < my_cnt; i++) {
            const uint4 g = xl4[sorted[my_start + i]];
            edge_acc(g, xrd, attv, z, agg);
        }
        __syncthreads();           // LDS reused next chunk
    }

    // finalize node d0: self-loop + normalize + leaky + jk + pooled sum
    float hh[4] = {0.f, 0.f, 0.f, 0.f};
    float cw = 0.f;
    int b = 0;
    if (d0 < N_NODES) {
        const uint4 g = xl4[d0];
        float xld[6];
        xld[0] = __builtin_bit_cast(float, g.x << 16);
        xld[1] = __builtin_bit_cast(float, g.x & 0xffff0000u);
        xld[2] = __builtin_bit_cast(float, g.y << 16);
        xld[3] = __builtin_bit_cast(float, g.y & 0xffff0000u);
        xld[4] = __builtin_bit_cast(float, g.z << 16);
        xld[5] = __builtin_bit_cast(float, g.z & 0xffff0000u);
        float sc = 0.f;
#pragma unroll
        for (int j = 0; j < 6; j++) {
            float e = xld[j] + xrd[j];
            e = (e >= 0.f) ? e : 0.2f * e;
            sc += attv[j] * e;
        }
        const float p = __expf(sc);
        const float zz = z + p;
#pragma unroll
        for (int c = 0; c < 4; c++) hh[c] = jkb[c];
#pragma unroll
        for (int j = 0; j < 6; j++) {
            float aj = (agg[j] + p * xld[j]) / zz + conv_b[j];
            aj = (aj >= 0.f) ? aj : 0.01f * aj;
#pragma unroll
            for (int c = 0; c < 4; c++) hh[c] += aj * jkW[j * 4 + c];
        }
        b = batch[d0];
        cw = 1.f;
    }
    const int b0 = __shfl(b, 0);
    if (__all(b == b0)) {
#pragma unroll
        for (int off2 = 32; off2 >= 1; off2 >>= 1) {
#pragma unroll
            for (int c = 0; c < 4; c++) hh[c] += __shfl_xor(hh[c], off2);
            cw += __shfl_xor(cw, off2);
        }
        if (lane == 0 && cw > 0.f) {
#pragma unroll
            for (int c = 0; c < 4; c++) atomicAdd(gsum + b0 * 4 + c, hh[c]);
            atomicAdd(gcnt + b0, cw);
        }
    } else if (cw > 0.f) {
#pragma unroll
        for (int c = 0; c < 4; c++) atomicAdd(gsum + b * 4 + c, hh[c]);
        atomicAdd(gcnt + b, cw);
    }
}

// cast-transpose W[K][N] f32 -> Wt[N][K] bf16
__global__ __launch_bounds__(256) void castT(
    const float* __restrict__ W, unsigned short* __restrict__ Wt, int K, int N)
{
    const int k = blockIdx.x * 256 + threadIdx.x;
    const int n = blockIdx.y;
    if (k < K) Wt[(size_t)n * K + k] = bf16rne(W[(size_t)k * N + n]);
}

// L1 GEMM: C[M,256] = A[M,2560](f32) @ Bt[256,2560](bf16)^T + bias.
// BM=64, BN=128, BK=64; 4 waves 2x2; 16 MFMA/wave/iter; XOR-swizzled LDS.
// Double-buffered: tile i+1's B-async + A-reg loads issued before compute
// on tile i; ONE barrier per iteration; load latency hidden behind MFMA.
__global__ __launch_bounds__(256) void mfma_gemm_l1(
    const float* __restrict__ A, const unsigned short* __restrict__ Bt,
    const float* __restrict__ bias, float* __restrict__ C,
    int M, int N, int K)
{
    __shared__ unsigned short As[2][64 * 64];
    __shared__ unsigned short Bs[2][128 * 64];
    const int t = threadIdx.x;
    const int w = t >> 6, l = t & 63;
    const int l15 = l & 15, quad = l >> 4;
    const int wm = (w & 1) * 32, wn = (w >> 1) * 64;
    const int gm0 = blockIdx.x * 64;
    const int gn0 = blockIdx.y * 128;
    const int r8 = l >> 3;
    const int c8 = (l & 7) ^ r8;
    const int ar = t >> 2;            // A staging: row 0..63
    const int ac0 = (t & 3) * 2;      // A staging: first of 2 chunks

    f32x4 acc[2][4];
#pragma unroll
    for (int mt = 0; mt < 2; mt++)
#pragma unroll
        for (int nt = 0; nt < 4; nt++) acc[mt][nt] = (f32x4){0.f, 0.f, 0.f, 0.f};

    const int niter = K / 64;

    // preload tile 0
#pragma unroll
    for (int c = 0; c < 4; c++) {
        const int j = w * 4 + c;
        async_cp16(Bt + (size_t)(gn0 + j * 8 + r8) * K + c8 * 8, &Bs[0][j * 512]);
    }
    {
        const float* src = A + (size_t)(gm0 + ar) * K + ac0 * 8;
        float4 v0 = *(const float4*)src;
        float4 v1 = *(const float4*)(src + 4);
        float4 v2 = *(const float4*)(src + 8);
        float4 v3 = *(const float4*)(src + 12);
        union { unsigned short h[8]; uint4 u; } p0, p1;
        p0.h[0] = bf16rne(v0.x); p0.h[1] = bf16rne(v0.y);
        p0.h[2] = bf16rne(v0.z); p0.h[3] = bf16rne(v0.w);
        p0.h[4] = bf16rne(v1.x); p0.h[5] = bf16rne(v1.y);
        p0.h[6] = bf16rne(v1.z); p0.h[7] = bf16rne(v1.w);
        p1.h[0] = bf16rne(v2.x); p1.h[1] = bf16rne(v2.y);
        p1.h[2] = bf16rne(v2.z); p1.h[3] = bf16rne(v2.w);
        p1.h[4] = bf16rne(v3.x); p1.h[5] = bf16rne(v3.y);
        p1.h[6] = bf16rne(v3.z); p1.h[7] = bf16rne(v3.w);
        *(uint4*)&As[0][ar * 64 + ((ac0 + 0) ^ (ar & 7)) * 8] = p0.u;
        *(uint4*)&As[0][ar * 64 + ((ac0 + 1) ^ (ar & 7)) * 8] = p1.u;
    }

    int p = 0;
    for (int i = 0; i < niter; i++) {
        __syncthreads();               // buf p ready (drains prev async+lds)
        const bool nxt = (i + 1 < niter);
        float4 v0, v1, v2, v3;
        if (nxt) {
            const int k1 = (i + 1) * 64;
#pragma unroll
            for (int c = 0; c < 4; c++) {
                const int j = w * 4 + c;
                async_cp16(Bt + (size_t)(gn0 + j * 8 + r8) * K + k1 + c8 * 8,
                           &Bs[p ^ 1][j * 512]);
            }
            const float* src = A + (size_t)(gm0 + ar) * K + k1 + ac0 * 8;
            v0 = *(const float4*)src;
            v1 = *(const float4*)(src + 4);
            v2 = *(const float4*)(src + 8);
            v3 = *(const float4*)(src + 12);
        }
        // compute on buffer p
#pragma unroll
        for (int kki = 0; kki < 2; kki++) {
            bf16x8 af[2], bfr[4];
#pragma unroll
            for (int mt = 0; mt < 2; mt++) {
                const int m = wm + mt * 16 + l15;
                af[mt] = *(const bf16x8*)&As[p][m * 64 + (((quad + 4 * kki) ^ (m & 7)) * 8)];
            }
#pragma unroll
            for (int nt = 0; nt < 4; nt++) {
                const int n = wn + nt * 16 + l15;
                bfr[nt] = *(const bf16x8*)&Bs[p][n * 64 + (((quad + 4 * kki) ^ (n & 7)) * 8)];
            }
#pragma unroll
            for (int mt = 0; mt < 2; mt++)
#pragma unroll
                for (int nt = 0; nt < 4; nt++)
                    acc[mt][nt] = __builtin_amdgcn_mfma_f32_16x16x32_bf16(
                        af[mt], bfr[nt], acc[mt][nt], 0, 0, 0);
        }
        if (nxt) {
            union { unsigned short h[8]; uint4 u; } p0, p1;
            p0.h[0] = bf16rne(v0.x); p0.h[1] = bf16rne(v0.y);
            p0.h[2] = bf16rne(v0.z); p0.h[3] = bf16rne(v0.w);
            p0.h[4] = bf16rne(v1.x); p0.h[5] = bf16rne(v1.y);
            p0.h[6] = bf16rne(v1.z); p0.h[7] = bf16rne(v1.w);
            p1.h[0] = bf16rne(v2.x); p1.h[1] = bf16rne(v2.y);
            p1.h[2] = bf16rne(v2.z); p1.h[3] = bf16rne(v2.w);
            p1.h[4] = bf16rne(v3.x); p1.h[5] = bf16rne(v3.y);
            p1.h[6] = bf16rne(v3.z); p1.h[7] = bf16rne(v3.w);
            *(uint4*)&As[p ^ 1][ar * 64 + ((ac0 + 0) ^ (ar & 7)) * 8] = p0.u;
            *(uint4*)&As[p ^ 1][ar * 64 + ((ac0 + 1) ^ (ar & 7)) * 8] = p1.u;
        }
        p ^= 1;
    }
#pragma unroll
    for (int nt = 0; nt < 4; nt++) {
        const int col = gn0 + wn + nt * 16 + l15;
        const float bv = bias[col];
#pragma unroll
        for (int mt = 0; mt < 2; mt++)
#pragma unroll
            for (int rr = 0; rr < 4; rr++) {
                const int row = gm0 + wm + mt * 16 + quad * 4 + rr;
                C[(size_t)row * N + col] = acc[mt][nt][rr] + bv;
            }
    }
}

// L2 GEMM: BM=32 x BN=64, A bf16 via async, Bt bf16.
__global__ __launch_bounds__(256) void mfma_gemm_l2(
    const unsigned short* __restrict__ Ab, const unsigned short* __restrict__ Bt,
    const float* __restrict__ bias, float* __restrict__ C,
    int M, int N, int K)
{
    __shared__ unsigned short As[32 * 64];
    __shared__ unsigned short Bs[64 * 64];
    const int t = threadIdx.x;
    const int w = t >> 6, l = t & 63;
    const int l15 = l & 15, quad = l >> 4;
    const int gm0 = blockIdx.x * 32;
    const int gn0 = blockIdx.y * 64;
    const int r8 = l >> 3;
    const int c8 = (l & 7) ^ r8;

    f32x4 acc[2];
    acc[0] = (f32x4){0.f, 0.f, 0.f, 0.f};
    acc[1] = (f32x4){0.f, 0.f, 0.f, 0.f};

    for (int k0 = 0; k0 < K; k0 += 64) {
#pragma unroll
        for (int c = 0; c < 2; c++) {
            const int j = w * 2 + c;
            async_cp16(Bt + (size_t)(gn0 + j * 8 + r8) * K + k0 + c8 * 8,
                       &Bs[j * 512]);
        }
        async_cp16(Ab + (size_t)(gm0 + w * 8 + r8) * K + k0 + c8 * 8, &As[w * 512]);
        __syncthreads();
#pragma unroll
        for (int kki = 0; kki < 2; kki++) {
            bf16x8 af[2], bfr;
#pragma unroll
            for (int mt = 0; mt < 2; mt++) {
                const int m = mt * 16 + l15;
                af[mt] = *(const bf16x8*)&As[m * 64 + (((quad + 4 * kki) ^ (m & 7)) * 8)];
            }
            const int n = w * 16 + l15;
            bfr = *(const bf16x8*)&Bs[n * 64 + (((quad + 4 * kki) ^ (n & 7)) * 8)];
#pragma unroll
            for (int mt = 0; mt < 2; mt++)
                acc[mt] = __builtin_amdgcn_mfma_f32_16x16x32_bf16(
                    af[mt], bfr, acc[mt], 0, 0, 0);
        }
        __syncthreads();
    }
    const int col = gn0 + w * 16 + l15;
    const float bv = bias[col];
#pragma unroll
    for (int mt = 0; mt < 2; mt++)
#pragma unroll
        for (int rr = 0; rr < 4; rr++) {
            const int row = gm0 + mt * 16 + quad * 4 + rr;
            C[(size_t)row * N + col] = acc[mt][rr] + bv;
        }
}

// LayerNorm(C=256) + leaky(0.01), f32 in -> bf16 out. One block per row.
__global__ __launch_bounds__(256) void ln_leaky_c256(
    const float* __restrict__ f, unsigned short* __restrict__ out,
    const float* __restrict__ g, const float* __restrict__ b)
{
    const int row = blockIdx.x;
    const int t = threadIdx.x;
    float v = f[(size_t)row * 256 + t];
    float s = v, s2 = v * v;
#pragma unroll
    for (int off = 32; off >= 1; off >>= 1) {
        s += __shfl_xor(s, off);
        s2 += __shfl_xor(s2, off);
    }
    __shared__ float ws[4], ws2[4];
    const int wid = t >> 6, lane = t & 63;
    if (lane == 0) { ws[wid] = s; ws2[wid] = s2; }
    __syncthreads();
    const float S = ws[0] + ws[1] + ws[2] + ws[3];
    const float S2 = ws2[0] + ws2[1] + ws2[2] + ws2[3];
    const float mu = S * (1.0f / 256.0f);
    const float var = S2 * (1.0f / 256.0f) - mu * mu;
    float y = (v - mu) * rsqrtf(var + 1e-5f) * g[t] + b[t];
    y = (y >= 0.f) ? y : 0.01f * y;
    out[(size_t)row * 256 + t] = bf16rne(y);
}

// In-place LayerNorm(C=64) + leaky(0.01). One wave per row, 4 rows/block.
__global__ __launch_bounds__(256) void ln_leaky_c64(
    float* __restrict__ f, const float* __restrict__ g, const float* __restrict__ b)
{
    const int wid = threadIdx.x >> 6, lane = threadIdx.x & 63;
    const int row = blockIdx.x * 4 + wid;
    float v = f[(size_t)row * 64 + lane];
    float s = v, s2 = v * v;
#pragma unroll
    for (int off = 32; off >= 1; off >>= 1) {
        s += __shfl_xor(s, off);
        s2 += __shfl_xor(s2, off);
    }
    const float mu = s * (1.0f / 64.0f);
    const float var = s2 * (1.0f / 64.0f) - mu * mu;
    float y = (v - mu) * rsqrtf(var + 1e-5f) * g[lane] + b[lane];
    f[(size_t)row * 64 + lane] = (y >= 0.f) ? y : 0.01f * y;
}

// f3 = leaky(LN(f2 @ W3 + b3)).  8 threads per row.
__global__ __launch_bounds__(256) void l3_ln_leaky(
    const float* __restrict__ f2, const float* __restrict__ W3,
    const float* __restrict__ b3,
    const float* __restrict__ g, const float* __restrict__ b,
    float* __restrict__ f3)
{
    __shared__ float sW[64 * 8];
    const int t = threadIdx.x;
    sW[t] = W3[t]; sW[t + 256] = W3[t + 256];
    __syncthreads();
    const int row = blockIdx.x * 32 + (t >> 3);
    const int c = t & 7;
    float acc = b3[c];
    const float* fr = f2 + (size_t)row * 64;
#pragma unroll 8
    for (int k = 0; k < 64; k++) acc += fr[k] * sW[k * 8 + c];
    float s = acc, s2 = acc * acc;
#pragma unroll
    for (int off = 4; off >= 1; off >>= 1) {
        s += __shfl_xor(s, off);
        s2 += __shfl_xor(s2, off);
    }
    const float mu = s * (1.0f / 8.0f);
    const float var = s2 * (1.0f / 8.0f) - mu * mu;
    float y = (acc - mu) * rsqrtf(var + 1e-5f) * g[c] + b[c];
    f3[(size_t)row * 8 + c] = (y >= 0.f) ? y : 0.01f * y;
}

// xf = leaky(LN(flat @ fl_W + fl_b)). One block per graph.
__global__ __launch_bounds__(256) void flat_ln_leaky(
    const float* __restrict__ f3, const float* __restrict__ W,
    const float* __restrict__ bb,
    const float* __restrict__ g, const float* __restrict__ b,
    float* __restrict__ xf)
{
    __shared__ float sf[1024];
    __shared__ float sp[8][32];
    const int t = threadIdx.x;
    const int gb = blockIdx.x;
    *(float4*)&sf[t * 4] = *(const float4*)(f3 + (size_t)gb * 1024 + t * 4);
    __syncthreads();
    const int c = t & 31, part = t >> 5;
    float acc = 0.f;
    for (int k = part * 128; k < part * 128 + 128; k++) acc += sf[k] * W[k * 32 + c];
    sp[part][c] = acc;
    __syncthreads();
    if (t < 32) {
        float v = bb[t];
#pragma unroll
        for (int p = 0; p < 8; p++) v += sp[p][t];
        float s = v, s2 = v * v;
#pragma unroll
        for (int off = 16; off >= 1; off >>= 1) {
            s += __shfl_xor(s, off);
            s2 += __shfl_xor(s2, off);
        }
        const float mu = s * (1.0f / 32.0f);
        const float var = s2 * (1.0f / 32.0f) - mu * mu;
        float y = (v - mu) * rsqrtf(var + 1e-5f) * g[t] + b[t];
        xf[gb * 32 + t] = (y >= 0.f) ? y : 0.01f * y;
    }
}

// out[b,o] = cat(gsum/cnt, xf, one_hot) @ out_W + out_b
__global__ __launch_bounds__(128) void final_out(
    const float* __restrict__ gsum, const float* __restrict__ gcnt,
    const float* __restrict__ xf, const float* __restrict__ onehot,
    const float* __restrict__ Wo, const float* __restrict__ bo,
    float* __restrict__ out)
{
    const int t = threadIdx.x;
    const int gb = t >> 1, o = t & 1;
    float cnt = gcnt[gb];
    cnt = (cnt > 1.f) ? cnt : 1.f;
    float acc = bo[o];
#pragma unroll
    for (int j = 0; j < 4; j++)  acc += (gsum[gb * 4 + j] / cnt) * Wo[j * 2 + o];
#pragma unroll
    for (int j = 0; j < 32; j++) acc += xf[gb * 32 + j] * Wo[(4 + j) * 2 + o];
#pragma unroll
    for (int j = 0; j < 20; j++) acc += onehot[gb * 20 + j] * Wo[(36 + j) * 2 + o];
    out[t] = acc;
}

extern "C" void kernel_launch(void* const* d_in, const int* in_sizes, int n_in,
                              void* d_out, int out_size, void* d_ws, size_t ws_size,
                              hipStream_t stream)
{
    const float* x        = (const float*)d_in[0];
    const int*   ei       = (const int*)d_in[1];
    const int*   batch    = (const int*)d_in[2];
    const float* features = (const float*)d_in[3];
    const float* one_hot  = (const float*)d_in[4];
    const float* W_l   = (const float*)d_in[5];
    const float* b_l   = (const float*)d_in[6];
    const float* W_r   = (const float*)d_in[7];
    const float* b_r   = (const float*)d_in[8];
    const float* att   = (const float*)d_in[9];
    const float* conv_b = (const float*)d_in[10];
    const float* jk_W  = (const float*)d_in[11];
    const float* jk_b  = (const float*)d_in[12];
    const float* l1_W  = (const float*)d_in[13];
    const float* l1_b  = (const float*)d_in[14];
    const float* ln1_g = (const float*)d_in[15];
    const float* ln1_b = (const float*)d_in[16];
    const float* l2_W  = (const float*)d_in[17];
    const float* l2_b  = (const float*)d_in[18];
    const float* ln2_g = (const float*)d_in[19];
    const float* ln2_b = (const float*)d_in[20];
    const float* l3_W  = (const float*)d_in[21];
    const float* l3_b  = (const float*)d_in[22];
    const float* ln3_g = (const float*)d_in[23];
    const float* ln3_b = (const float*)d_in[24];
    const float* fl_W  = (const float*)d_in[25];
    const float* fl_b  = (const float*)d_in[26];
    const float* ln4_g = (const float*)d_in[27];
    const float* ln4_b = (const float*)d_in[28];
    const float* out_W = (const float*)d_in[29];
    const float* out_b = (const float*)d_in[30];
    (void)in_sizes; (void)n_in; (void)out_size; (void)ws_size;

    float* ws = (float*)d_ws;
    unsigned short* xlb = (unsigned short*)(ws + 0);
    float* xr   = ws + 800000;
    unsigned short* w1t = (unsigned short*)(ws + 2400000);
    unsigned short* w2t = (unsigned short*)(ws + 2727680);
    float* gsum   = ws + 2735872;
    float* gcnt   = ws + 2736128;
    int*   cursor = (int*)(ws + 2736192);          // [782]
    // union @ 2,737,024
    int* pairs = (int*)(ws + 2737024);             // 782*8960 = 7,006,720 ints
    float* f1           = ws + 2737024;            // 8192*256
    unsigned short* f1b = (unsigned short*)(ws + 4834176);
    float* f2           = ws + 5358464;            // 8192*64
    float* f3           = ws + 5882752;            // 8192*8
    float* xf           = ws + 5948288;            // 64*32

    // zero gsum+gcnt+cursor (contiguous 1102 dwords)
    hipMemsetAsync(gsum, 0, 1102 * sizeof(float), stream);

    node_xform<<<N_NODES / 16, 256, 0, stream>>>(x, W_l, b_l, W_r, b_r, xlb, xr);
    edge_bucket<<<EBLK, 256, 0, stream>>>(ei, cursor, pairs);
    castT<<<dim3(10, 256), 256, 0, stream>>>(l1_W, w1t, FEAT, 256);
    castT<<<dim3(1, 64), 256, 0, stream>>>(l2_W, w2t, 256, 64);
    bucket_reduce<<<NBK, 256, 0, stream>>>(pairs, cursor, xlb, xr, att, conv_b,
                                           jk_W, jk_b, batch, gsum, gcnt);
    mfma_gemm_l1<<<dim3(MROWS / 64, 2), 256, 0, stream>>>(
        features, w1t, l1_b, f1, MROWS, 256, FEAT);
    ln_leaky_c256<<<MROWS, 256, 0, stream>>>(f1, f1b, ln1_g, ln1_b);
    mfma_gemm_l2<<<dim3(MROWS / 32, 1), 256, 0, stream>>>(
        f1b, w2t, l2_b, f2, MROWS, 64, 256);
    ln_leaky_c64<<<MROWS / 4, 256, 0, stream>>>(f2, ln2_g, ln2_b);
    l3_ln_leaky<<<MROWS / 32, 256, 0, stream>>>(f2, l3_W, l3_b, ln3_g, ln3_b, f3);
    flat_ln_leaky<<<NB, 256, 0, stream>>>(f3, fl_W, fl_b, ln4_g, ln4_b, xf);
    final_out<<<1, 128, 0, stream>>>(gsum, gcnt, xf, one_hot, out_W, out_b, (float*)d_out);
}

// Round 4
// 541.724 us; speedup vs baseline: 1.1382x; 1.1382x over previous
//
#include <hip/hip_runtime.h>
#include <cstdint>
#include <cstddef>

#define N_NODES 200000
#define N_EDGES 6400000
#define NB      64
#define MROWS   8192     // NB*ROWS
#define FEAT    2560

// edge bucketing: bucket = 256 consecutive dst nodes
#define BSZ   256
#define NBK   782        // ceil(200000/256)
#define EBLK  512        // edge_bucket role blocks
#define ETILE 12500      // edges per block (EBLK*ETILE == N_EDGES)
#define BCAP  8960       // per-bucket region capacity (mean 8187, sd ~90)
#define NXB   768        // node_xform role blocks (grid-strided over 12500 groups)
#define GEMMB 256        // gemm_l1 role blocks (128 x 2)

typedef __attribute__((ext_vector_type(8))) short bf16x8;
typedef __attribute__((ext_vector_type(4))) float f32x4;

__device__ __forceinline__ unsigned short bf16rne(float f) {
    unsigned u = __builtin_bit_cast(unsigned, f);
    u += 0x7fffu + ((u >> 16) & 1u);
    return (unsigned short)(u >> 16);
}

__device__ __forceinline__ void async_cp16(const void* g, void* l) {
    __builtin_amdgcn_global_load_lds(
        (const __attribute__((address_space(1))) unsigned int*)g,
        (__attribute__((address_space(3))) unsigned int*)l, 16, 0, 0);
}

// unpack bf16x6 gather, accumulate one edge into register z/agg
__device__ __forceinline__ void edge_acc(
    uint4 g, const float* xrd, const float* attv, float& z, float* agg)
{
    float xls[6];
    xls[0] = __builtin_bit_cast(float, g.x << 16);
    xls[1] = __builtin_bit_cast(float, g.x & 0xffff0000u);
    xls[2] = __builtin_bit_cast(float, g.y << 16);
    xls[3] = __builtin_bit_cast(float, g.y & 0xffff0000u);
    xls[4] = __builtin_bit_cast(float, g.z << 16);
    xls[5] = __builtin_bit_cast(float, g.z & 0xffff0000u);
    float sc = 0.f;
#pragma unroll
    for (int j = 0; j < 6; j++) {
        float e = xls[j] + xrd[j];
        e = (e >= 0.f) ? e : 0.2f * e;
        sc += attv[j] * e;
    }
    const float p = __expf(sc);
    z += p;
#pragma unroll
    for (int j = 0; j < 6; j++) agg[j] += p * xls[j];
}

// ---------------------------------------------------------------------------
// Workspace layout (4-byte units):
//   xlb  (bf16[200000][8])   @ 0
//   xr   (f32 [200000][8])   @ 800,000
//   w1t  (bf16[256][2560])   @ 2,400,000
//   w2t  (bf16[64][256])     @ 2,727,680
//   gsum [256] @2,735,872 ; gcnt [64] @2,736,128 ; cursor [782] @2,736,192
//     (memset span: 1102 dw from gsum)
//   pairs[782*8960] @ 2,737,024 .. 9,743,744
//   FUSED path (needs ws >= 53.9 MB; f1 written CONCURRENTLY with pairs):
//     f1 f32 @9,743,744; f1b bf16 @11,840,896; f2 @12,889,472;
//     f3 @13,413,760; xf @13,479,296 .. 13,481,344  (53.9 MB)
//   FALLBACK path (serial; mlp scratch aliased over pairs as before):
//     f1 @2,737,024; f1b @4,834,176; f2 @5,358,464; f3 @5,882,752;
//     xf @5,948,288
// ---------------------------------------------------------------------------

// node transform body: groups of 16 nodes, grid-strided with given stride.
__device__ __forceinline__ void nx_body(
    const int nxi, const int nstride,
    const float* __restrict__ x,
    const float* __restrict__ Wl, const float* __restrict__ bl,
    const float* __restrict__ Wr, const float* __restrict__ br,
    unsigned short* __restrict__ xlb, float* __restrict__ xr)
{
    const int t = threadIdx.x;
    const int l = t & 15;

    float wl[48], wr[48];
#pragma unroll
    for (int q = 0; q < 12; q++) {
        *(float4*)&wl[q * 4] = *(const float4*)(Wl + 48 * l + 4 * q);
        *(float4*)&wr[q * 4] = *(const float4*)(Wr + 48 * l + 4 * q);
    }
    for (int g = nxi; g < N_NODES / 16; g += nstride) {
        const int node = g * 16 + (t >> 4);
        float xv[8];
        *(float4*)&xv[0] = *(const float4*)(x + (size_t)node * 128 + l * 8);
        *(float4*)&xv[4] = *(const float4*)(x + (size_t)node * 128 + l * 8 + 4);

        float al[6] = {}, ar[6] = {};
#pragma unroll
        for (int i = 0; i < 8; i++) {
#pragma unroll
            for (int j = 0; j < 6; j++) {
                al[j] += xv[i] * wl[i * 6 + j];
                ar[j] += xv[i] * wr[i * 6 + j];
            }
        }
#pragma unroll
        for (int off = 8; off >= 1; off >>= 1) {
#pragma unroll
            for (int j = 0; j < 6; j++) {
                al[j] += __shfl_xor(al[j], off);
                ar[j] += __shfl_xor(ar[j], off);
            }
        }
        if (l == 0) {
            union { unsigned short h[8]; uint4 v; } u;
#pragma unroll
            for (int j = 0; j < 6; j++) u.h[j] = bf16rne(al[j] + bl[j]);
            u.h[6] = 0; u.h[7] = 0;
            *(uint4*)(xlb + (size_t)node * 8) = u.v;
            float4 r0; float2 r1;
            r0.x = ar[0] + br[0]; r0.y = ar[1] + br[1];
            r0.z = ar[2] + br[2]; r0.w = ar[3] + br[3];
            r1.x = ar[4] + br[4]; r1.y = ar[5] + br[5];
            *(float4*)(xr + (size_t)node * 8) = r0;
            *(float2*)(xr + (size_t)node * 8 + 4) = r1;
        }
    }
}

// LDS counting-sort bucketizer body (round-1 proven config: ETILE=12500).
// pairs = src<<8 | dst&255.
__device__ __forceinline__ void eb_body(
    const int bid, char* smem,
    const int* __restrict__ ei, int* __restrict__ cursor, int* __restrict__ pairs)
{
    int* sorted = (int*)smem;          // [ETILE]
    int* hb     = sorted + ETILE;      // [NBK+1] exclusive bucket starts
    int* cur    = hb + NBK + 1;        // [NBK]   hist, then scatter cursor
    int* gbl    = cur + NBK;           // [NBK]   reserved global span base
    int* wsum   = gbl + NBK;           // [4]
    const int t = threadIdx.x;
    const int lane = t & 63, wid = t >> 6;
    const int base = bid * ETILE;

    for (int b = t; b < NBK; b += 256) cur[b] = 0;
    __syncthreads();

    // pass 1: histogram dst buckets (dst re-read in pass 2 from L2)
    for (int i = t; i < ETILE; i += 256)
        atomicAdd(&cur[ei[N_EDGES + base + i] >> 8], 1);
    __syncthreads();

    // block-wide exclusive prefix: thread t owns buckets 4t..4t+3
    int c[4]; int lsum = 0;
#pragma unroll
    for (int q = 0; q < 4; q++) {
        const int b = 4 * t + q;
        c[q] = (b < NBK) ? cur[b] : 0;
        lsum += c[q];
    }
    int v = lsum;
#pragma unroll
    for (int d = 1; d < 64; d <<= 1) {
        const int o = __shfl_up(v, d);
        if (lane >= d) v += o;
    }
    if (lane == 63) wsum[wid] = v;
    __syncthreads();                    // also orders cur[] reads vs rewrite
    int off = 0;
#pragma unroll
    for (int w = 0; w < 3; w++) if (w < wid) off += wsum[w];
    int run = off + v - lsum;           // exclusive start for bucket 4t

    // reserve global spans now; results consumed after pass 2
    int mygb[4];
#pragma unroll
    for (int q = 0; q < 4; q++) {
        const int b = 4 * t + q;
        mygb[q] = (b < NBK && c[q] > 0) ? atomicAdd(&cursor[b], c[q]) : 0;
    }

#pragma unroll
    for (int q = 0; q < 4; q++) {
        const int b = 4 * t + q;
        if (b <= NBK) hb[b] = run;      // hb[NBK] = ETILE total
        if (b < NBK) cur[b] = run;      // becomes scatter cursor
        run += c[q];
    }
    __syncthreads();

    // pass 2: LDS counting-sort scatter (pure LDS per edge)
    for (int i = t; i < ETILE; i += 256) {
        const int d = ei[N_EDGES + base + i];
        const int s = ei[base + i];
        const int pos = atomicAdd(&cur[d >> 8], 1);
        sorted[pos] = (s << 8) | (d & 255);
    }
#pragma unroll
    for (int q = 0; q < 4; q++) {
        const int b = 4 * t + q;
        if (b < NBK) gbl[b] = mygb[q];  // waits on atomics here (hidden)
    }
    __syncthreads();

    // copy-out: 16-lane group per bucket -> full-line contiguous span writes
    const int grp = t >> 4, gl = t & 15;
    for (int b = grp; b < NBK; b += 16) {
        const int st = hb[b];
        const int cnt = hb[b + 1] - st;
        int* dst = pairs + b * BCAP + gbl[b];
        for (int i = gl; i < cnt; i += 16)
            dst[i] = sorted[st + i];
    }
}

// L1 GEMM body: C[8192,256] = A[8192,2560](f32) @ Bt[256,2560](bf16)^T + bias.
// BM=64, BN=128, BK=64; 4 waves 2x2; XOR-swizzled LDS; double-buffered.
__device__ __forceinline__ void gemm_l1_body(
    const int bx, const int by, char* smem,
    const float* __restrict__ A, const unsigned short* __restrict__ Bt,
    const float* __restrict__ bias, float* __restrict__ C)
{
    unsigned short (*As)[64 * 64] = (unsigned short(*)[64 * 64])smem;
    unsigned short (*Bs)[128 * 64] =
        (unsigned short(*)[128 * 64])(smem + 2 * 64 * 64 * sizeof(short));
    const int K = FEAT, N = 256;
    const int t = threadIdx.x;
    const int w = t >> 6, l = t & 63;
    const int l15 = l & 15, quad = l >> 4;
    const int wm = (w & 1) * 32, wn = (w >> 1) * 64;
    const int gm0 = bx * 64;
    const int gn0 = by * 128;
    const int r8 = l >> 3;
    const int c8 = (l & 7) ^ r8;
    const int ar = t >> 2;            // A staging: row 0..63
    const int ac0 = (t & 3) * 2;      // A staging: first of 2 chunks

    f32x4 acc[2][4];
#pragma unroll
    for (int mt = 0; mt < 2; mt++)
#pragma unroll
        for (int nt = 0; nt < 4; nt++) acc[mt][nt] = (f32x4){0.f, 0.f, 0.f, 0.f};

    const int niter = K / 64;

    // preload tile 0
#pragma unroll
    for (int c = 0; c < 4; c++) {
        const int j = w * 4 + c;
        async_cp16(Bt + (size_t)(gn0 + j * 8 + r8) * K + c8 * 8, &Bs[0][j * 512]);
    }
    {
        const float* src = A + (size_t)(gm0 + ar) * K + ac0 * 8;
        float4 v0 = *(const float4*)src;
        float4 v1 = *(const float4*)(src + 4);
        float4 v2 = *(const float4*)(src + 8);
        float4 v3 = *(const float4*)(src + 12);
        union { unsigned short h[8]; uint4 u; } p0, p1;
        p0.h[0] = bf16rne(v0.x); p0.h[1] = bf16rne(v0.y);
        p0.h[2] = bf16rne(v0.z); p0.h[3] = bf16rne(v0.w);
        p0.h[4] = bf16rne(v1.x); p0.h[5] = bf16rne(v1.y);
        p0.h[6] = bf16rne(v1.z); p0.h[7] = bf16rne(v1.w);
        p1.h[0] = bf16rne(v2.x); p1.h[1] = bf16rne(v2.y);
        p1.h[2] = bf16rne(v2.z); p1.h[3] = bf16rne(v2.w);
        p1.h[4] = bf16rne(v3.x); p1.h[5] = bf16rne(v3.y);
        p1.h[6] = bf16rne(v3.z); p1.h[7] = bf16rne(v3.w);
        *(uint4*)&As[0][ar * 64 + ((ac0 + 0) ^ (ar & 7)) * 8] = p0.u;
        *(uint4*)&As[0][ar * 64 + ((ac0 + 1) ^ (ar & 7)) * 8] = p1.u;
    }

    int p = 0;
    for (int i = 0; i < niter; i++) {
        __syncthreads();               // buf p ready (drains prev async+lds)
        const bool nxt = (i + 1 < niter);
        float4 v0, v1, v2, v3;
        if (nxt) {
            const int k1 = (i + 1) * 64;
#pragma unroll
            for (int c = 0; c < 4; c++) {
                const int j = w * 4 + c;
                async_cp16(Bt + (size_t)(gn0 + j * 8 + r8) * K + k1 + c8 * 8,
                           &Bs[p ^ 1][j * 512]);
            }
            const float* src = A + (size_t)(gm0 + ar) * K + k1 + ac0 * 8;
            v0 = *(const float4*)src;
            v1 = *(const float4*)(src + 4);
            v2 = *(const float4*)(src + 8);
            v3 = *(const float4*)(src + 12);
        }
        // compute on buffer p
#pragma unroll
        for (int kki = 0; kki < 2; kki++) {
            bf16x8 af[2], bfr[4];
#pragma unroll
            for (int mt = 0; mt < 2; mt++) {
                const int m = wm + mt * 16 + l15;
                af[mt] = *(const bf16x8*)&As[p][m * 64 + (((quad + 4 * kki) ^ (m & 7)) * 8)];
            }
#pragma unroll
            for (int nt = 0; nt < 4; nt++) {
                const int n = wn + nt * 16 + l15;
                bfr[nt] = *(const bf16x8*)&Bs[p][n * 64 + (((quad + 4 * kki) ^ (n & 7)) * 8)];
            }
#pragma unroll
            for (int mt = 0; mt < 2; mt++)
#pragma unroll
                for (int nt = 0; nt < 4; nt++)
                    acc[mt][nt] = __builtin_amdgcn_mfma_f32_16x16x32_bf16(
                        af[mt], bfr[nt], acc[mt][nt], 0, 0, 0);
        }
        if (nxt) {
            union { unsigned short h[8]; uint4 u; } p0, p1;
            p0.h[0] = bf16rne(v0.x); p0.h[1] = bf16rne(v0.y);
            p0.h[2] = bf16rne(v0.z); p0.h[3] = bf16rne(v0.w);
            p0.h[4] = bf16rne(v1.x); p0.h[5] = bf16rne(v1.y);
            p0.h[6] = bf16rne(v1.z); p0.h[7] = bf16rne(v1.w);
            p1.h[0] = bf16rne(v2.x); p1.h[1] = bf16rne(v2.y);
            p1.h[2] = bf16rne(v2.z); p1.h[3] = bf16rne(v2.w);
            p1.h[4] = bf16rne(v3.x); p1.h[5] = bf16rne(v3.y);
            p1.h[6] = bf16rne(v3.z); p1.h[7] = bf16rne(v3.w);
            *(uint4*)&As[p ^ 1][ar * 64 + ((ac0 + 0) ^ (ar & 7)) * 8] = p0.u;
            *(uint4*)&As[p ^ 1][ar * 64 + ((ac0 + 1) ^ (ar & 7)) * 8] = p1.u;
        }
        p ^= 1;
    }
#pragma unroll
    for (int nt = 0; nt < 4; nt++) {
        const int col = gn0 + wn + nt * 16 + l15;
        const float bv = bias[col];
#pragma unroll
        for (int mt = 0; mt < 2; mt++)
#pragma unroll
            for (int rr = 0; rr < 4; rr++) {
                const int row = gm0 + wm + mt * 16 + quad * 4 + rr;
                C[(size_t)row * N + col] = acc[mt][nt][rr] + bv;
            }
    }
}

// ------------------------- standalone kernels (fallback) --------------------

__global__ __launch_bounds__(256) void node_xform(
    const float* __restrict__ x,
    const float* __restrict__ Wl, const float* __restrict__ bl,
    const float* __restrict__ Wr, const float* __restrict__ br,
    unsigned short* __restrict__ xlb, float* __restrict__ xr)
{
    nx_body(blockIdx.x, N_NODES / 16, x, Wl, bl, Wr, br, xlb, xr);
}

__global__ __launch_bounds__(256) void edge_bucket(
    const int* __restrict__ ei, int* __restrict__ cursor, int* __restrict__ pairs)
{
    __shared__ __align__(16) char smem[59408];
    eb_body(blockIdx.x, smem, ei, cursor, pairs);
}

__global__ __launch_bounds__(256) void mfma_gemm_l1(
    const float* __restrict__ A, const unsigned short* __restrict__ Bt,
    const float* __restrict__ bias, float* __restrict__ C)
{
    __shared__ __align__(16) char smem[49152];
    gemm_l1_body(blockIdx.x, blockIdx.y, smem, A, Bt, bias, C);
}

// ------------------------- fused front (needs de-aliased f1) ----------------
// 1536 blocks, role = bid % 3 (interleaved for mixing).
//   role 0           -> eb   (q in [0,512))
//   role 1, q < 256  -> gemm (bx = q&127, by = q>>7)
//   role 1, q >= 256 -> nx   (nxi = 512 + q-256)
//   role 2           -> nx   (nxi = q)
__global__ __launch_bounds__(256) void fused_front(
    const float* __restrict__ x,
    const float* __restrict__ Wl, const float* __restrict__ bl,
    const float* __restrict__ Wr, const float* __restrict__ br,
    unsigned short* __restrict__ xlb, float* __restrict__ xr,
    const int* __restrict__ ei, int* __restrict__ cursor, int* __restrict__ pairs,
    const float* __restrict__ A, const unsigned short* __restrict__ Bt,
    const float* __restrict__ bias, float* __restrict__ C)
{
    __shared__ __align__(16) char smem[59408];   // max(eb 59404, gemm 49152)
    const int bid = blockIdx.x;
    const int role = bid % 3;
    const int q = bid / 3;
    if (role == 0) {
        eb_body(q, smem, ei, cursor, pairs);
    } else if (role == 1 && q < GEMMB) {
        gemm_l1_body(q & 127, q >> 7, smem, A, Bt, bias, C);
    } else {
        const int nxi = (role == 2) ? q : EBLK + (q - GEMMB);
        nx_body(nxi, NXB, x, Wl, bl, Wr, br, xlb, xr);
    }
}

// One block per 256-node bucket. In-LDS counting sort by local dst, then
// thread t owns dst t: walks its contiguous run, accumulates in registers.
// Fused finalize + jk + pooled segment-mean.
__global__ __launch_bounds__(256) void bucket_reduce(
    const int* __restrict__ pairs, const int* __restrict__ cursor,
    const unsigned short* __restrict__ xlb, const float* __restrict__ xr,
    const float* __restrict__ att, const float* __restrict__ conv_b,
    const float* __restrict__ jkW, const float* __restrict__ jkb,
    const int* __restrict__ batch,
    float* __restrict__ gsum, float* __restrict__ gcnt)
{
    __shared__ int sorted[BCAP];
    __shared__ int hist[256];     // histogram, then scatter cursor
    __shared__ int wtot[4];
    const int t = threadIdx.x;
    const int lane = t & 63, wid = t >> 6;
    const int d0 = blockIdx.x * BSZ + t;

    float xrd[6];
    if (d0 < N_NODES) {
        float4 a = *(const float4*)(xr + (size_t)d0 * 8);
        float2 b = *(const float2*)(xr + (size_t)d0 * 8 + 4);
        xrd[0] = a.x; xrd[1] = a.y; xrd[2] = a.z;
        xrd[3] = a.w; xrd[4] = b.x; xrd[5] = b.y;
    } else {
#pragma unroll
        for (int j = 0; j < 6; j++) xrd[j] = 0.f;
    }
    float attv[6];
#pragma unroll
    for (int j = 0; j < 6; j++) attv[j] = att[j];

    float z = 0.f, agg[6] = {};
    const uint4* xl4 = (const uint4*)xlb;
    const int e0 = blockIdx.x * BCAP;
    const int e1 = e0 + cursor[blockIdx.x];

    for (int c0 = e0; c0 < e1; c0 += BCAP) {
        const int rem = e1 - c0;
        const int cnt_chunk = (rem < BCAP) ? rem : BCAP;
        hist[t] = 0;
        __syncthreads();
        for (int i = t; i < cnt_chunk; i += 256)
            atomicAdd(&hist[pairs[c0 + i] & 255], 1);
        __syncthreads();
        // exclusive prefix: wave shfl-scan + cross-wave offsets
        const int h = hist[t];
        int v = h;
#pragma unroll
        for (int d = 1; d < 64; d <<= 1) {
            int o = __shfl_up(v, d);
            if (lane >= d) v += o;
        }
        if (lane == 63) wtot[wid] = v;
        __syncthreads();
        int off = 0;
#pragma unroll
        for (int wv = 0; wv < 3; wv++) if (wv < wid) off += wtot[wv];
        const int my_start = v - h + off;
        const int my_cnt = h;
        __syncthreads();
        hist[t] = my_start;        // becomes scatter cursor
        __syncthreads();
        for (int i = t; i < cnt_chunk; i += 256) {
            const int pv = pairs[c0 + i];
            const int pos = atomicAdd(&hist[pv & 255], 1);
            sorted[pos] = ((unsigned)pv) >> 8;
        }
        __syncthreads();
        // walk my run: 4-wide batched gathers (independent -> pipelined)
        int i = 0;
        for (; i + 4 <= my_cnt; i += 4) {
            const int s0 = sorted[my_start + i];
            const int s1 = sorted[my_start + i + 1];
            const int s2 = sorted[my_start + i + 2];
            const int s3 = sorted[my_start + i + 3];
            const uint4 g0 = xl4[s0], g1 = xl4[s1], g2 = xl4[s2], g3 = xl4[s3];
            edge_acc(g0, xrd, attv, z, agg);
            edge_acc(g1, xrd, attv, z, agg);
            edge_acc(g2, xrd, attv, z, agg);
            edge_acc(g3, xrd, attv, z, agg);
        }
        for (; i < my_cnt; i++) {
            const uint4 g = xl4[sorted[my_start + i]];
            edge_acc(g, xrd, attv, z, agg);
        }
        __syncthreads();           // LDS reused next chunk
    }

    // finalize node d0: self-loop + normalize + leaky + jk + pooled sum
    float hh[4] = {0.f, 0.f, 0.f, 0.f};
    float cw = 0.f;
    int b = 0;
    if (d0 < N_NODES) {
        const uint4 g = xl4[d0];
        float xld[6];
        xld[0] = __builtin_bit_cast(float, g.x << 16);
        xld[1] = __builtin_bit_cast(float, g.x & 0xffff0000u);
        xld[2] = __builtin_bit_cast(float, g.y << 16);
        xld[3] = __builtin_bit_cast(float, g.y & 0xffff0000u);
        xld[4] = __builtin_bit_cast(float, g.z << 16);
        xld[5] = __builtin_bit_cast(float, g.z & 0xffff0000u);
        float sc = 0.f;
#pragma unroll
        for (int j = 0; j < 6; j++) {
            float e = xld[j] + xrd[j];
            e = (e >= 0.f) ? e : 0.2f * e;
            sc += attv[j] * e;
        }
        const float p = __expf(sc);
        const float zz = z + p;
#pragma unroll
        for (int c = 0; c < 4; c++) hh[c] = jkb[c];
#pragma unroll
        for (int j = 0; j < 6; j++) {
            float aj = (agg[j] + p * xld[j]) / zz + conv_b[j];
            aj = (aj >= 0.f) ? aj : 0.01f * aj;
#pragma unroll
            for (int c = 0; c < 4; c++) hh[c] += aj * jkW[j * 4 + c];
        }
        b = batch[d0];
        cw = 1.f;
    }
    const int b0 = __shfl(b, 0);
    if (__all(b == b0)) {
#pragma unroll
        for (int off2 = 32; off2 >= 1; off2 >>= 1) {
#pragma unroll
            for (int c = 0; c < 4; c++) hh[c] += __shfl_xor(hh[c], off2);
            cw += __shfl_xor(cw, off2);
        }
        if (lane == 0 && cw > 0.f) {
#pragma unroll
            for (int c = 0; c < 4; c++) atomicAdd(gsum + b0 * 4 + c, hh[c]);
            atomicAdd(gcnt + b0, cw);
        }
    } else if (cw > 0.f) {
#pragma unroll
        for (int c = 0; c < 4; c++) atomicAdd(gsum + b * 4 + c, hh[c]);
        atomicAdd(gcnt + b, cw);
    }
}

// cast-transpose W[K][N] f32 -> Wt[N][K] bf16
__global__ __launch_bounds__(256) void castT(
    const float* __restrict__ W, unsigned short* __restrict__ Wt, int K, int N)
{
    const int k = blockIdx.x * 256 + threadIdx.x;
    const int n = blockIdx.y;
    if (k < K) Wt[(size_t)n * K + k] = bf16rne(W[(size_t)k * N + n]);
}

// L2 GEMM: BM=32 x BN=64, A bf16 via async, Bt bf16.
__global__ __launch_bounds__(256) void mfma_gemm_l2(
    const unsigned short* __restrict__ Ab, const unsigned short* __restrict__ Bt,
    const float* __restrict__ bias, float* __restrict__ C,
    int M, int N, int K)
{
    __shared__ unsigned short As[32 * 64];
    __shared__ unsigned short Bs[64 * 64];
    const int t = threadIdx.x;
    const int w = t >> 6, l = t & 63;
    const int l15 = l & 15, quad = l >> 4;
    const int gm0 = blockIdx.x * 32;
    const int gn0 = blockIdx.y * 64;
    const int r8 = l >> 3;
    const int c8 = (l & 7) ^ r8;

    f32x4 acc[2];
    acc[0] = (f32x4){0.f, 0.f, 0.f, 0.f};
    acc[1] = (f32x4){0.f, 0.f, 0.f, 0.f};

    for (int k0 = 0; k0 < K; k0 += 64) {
#pragma unroll
        for (int c = 0; c < 2; c++) {
            const int j = w * 2 + c;
            async_cp16(Bt + (size_t)(gn0 + j * 8 + r8) * K + k0 + c8 * 8,
                       &Bs[j * 512]);
        }
        async_cp16(Ab + (size_t)(gm0 + w * 8 + r8) * K + k0 + c8 * 8, &As[w * 512]);
        __syncthreads();
#pragma unroll
        for (int kki = 0; kki < 2; kki++) {
            bf16x8 af[2], bfr;
#pragma unroll
            for (int mt = 0; mt < 2; mt++) {
                const int m = mt * 16 + l15;
                af[mt] = *(const bf16x8*)&As[m * 64 + (((quad + 4 * kki) ^ (m & 7)) * 8)];
            }
            const int n = w * 16 + l15;
            bfr = *(const bf16x8*)&Bs[n * 64 + (((quad + 4 * kki) ^ (n & 7)) * 8)];
#pragma unroll
            for (int mt = 0; mt < 2; mt++)
                acc[mt] = __builtin_amdgcn_mfma_f32_16x16x32_bf16(
                    af[mt], bfr, acc[mt], 0, 0, 0);
        }
        __syncthreads();
    }
    const int col = gn0 + w * 16 + l15;
    const float bv = bias[col];
#pragma unroll
    for (int mt = 0; mt < 2; mt++)
#pragma unroll
        for (int rr = 0; rr < 4; rr++) {
            const int row = gm0 + mt * 16 + quad * 4 + rr;
            C[(size_t)row * N + col] = acc[mt][rr] + bv;
        }
}

// LayerNorm(C=256) + leaky(0.01), f32 in -> bf16 out. One block per row.
__global__ __launch_bounds__(256) void ln_leaky_c256(
    const float* __restrict__ f, unsigned short* __restrict__ out,
    const float* __restrict__ g, const float* __restrict__ b)
{
    const int row = blockIdx.x;
    const int t = threadIdx.x;
    float v = f[(size_t)row * 256 + t];
    float s = v, s2 = v * v;
#pragma unroll
    for (int off = 32; off >= 1; off >>= 1) {
        s += __shfl_xor(s, off);
        s2 += __shfl_xor(s2, off);
    }
    __shared__ float ws[4], ws2[4];
    const int wid = t >> 6, lane = t & 63;
    if (lane == 0) { ws[wid] = s; ws2[wid] = s2; }
    __syncthreads();
    const float S = ws[0] + ws[1] + ws[2] + ws[3];
    const float S2 = ws2[0] + ws2[1] + ws2[2] + ws2[3];
    const float mu = S * (1.0f / 256.0f);
    const float var = S2 * (1.0f / 256.0f) - mu * mu;
    float y = (v - mu) * rsqrtf(var + 1e-5f) * g[t] + b[t];
    y = (y >= 0.f) ? y : 0.01f * y;
    out[(size_t)row * 256 + t] = bf16rne(y);
}

// In-place LayerNorm(C=64) + leaky(0.01). One wave per row, 4 rows/block.
__global__ __launch_bounds__(256) void ln_leaky_c64(
    float* __restrict__ f, const float* __restrict__ g, const float* __restrict__ b)
{
    const int wid = threadIdx.x >> 6, lane = threadIdx.x & 63;
    const int row = blockIdx.x * 4 + wid;
    float v = f[(size_t)row * 64 + lane];
    float s = v, s2 = v * v;
#pragma unroll
    for (int off = 32; off >= 1; off >>= 1) {
        s += __shfl_xor(s, off);
        s2 += __shfl_xor(s2, off);
    }
    const float mu = s * (1.0f / 64.0f);
    const float var = s2 * (1.0f / 64.0f) - mu * mu;
    float y = (v - mu) * rsqrtf(var + 1e-5f) * g[lane] + b[lane];
    f[(size_t)row * 64 + lane] = (y >= 0.f) ? y : 0.01f * y;
}

// f3 = leaky(LN(f2 @ W3 + b3)).  8 threads per row.
__global__ __launch_bounds__(256) void l3_ln_leaky(
    const float* __restrict__ f2, const float* __restrict__ W3,
    const float* __restrict__ b3,
    const float* __restrict__ g, const float* __restrict__ b,
    float* __restrict__ f3)
{
    __shared__ float sW[64 * 8];
    const int t = threadIdx.x;
    sW[t] = W3[t]; sW[t + 256] = W3[t + 256];
    __syncthreads();
    const int row = blockIdx.x * 32 + (t >> 3);
    const int c = t & 7;
    float acc = b3[c];
    const float* fr = f2 + (size_t)row * 64;
#pragma unroll 8
    for (int k = 0; k < 64; k++) acc += fr[k] * sW[k * 8 + c];
    float s = acc, s2 = acc * acc;
#pragma unroll
    for (int off = 4; off >= 1; off >>= 1) {
        s += __shfl_xor(s, off);
        s2 += __shfl_xor(s2, off);
    }
    const float mu = s * (1.0f / 8.0f);
    const float var = s2 * (1.0f / 8.0f) - mu * mu;
    float y = (acc - mu) * rsqrtf(var + 1e-5f) * g[c] + b[c];
    f3[(size_t)row * 8 + c] = (y >= 0.f) ? y : 0.01f * y;
}

// xf = leaky(LN(flat @ fl_W + fl_b)). One block per graph.
__global__ __launch_bounds__(256) void flat_ln_leaky(
    const float* __restrict__ f3, const float* __restrict__ W,
    const float* __restrict__ bb,
    const float* __restrict__ g, const float* __restrict__ b,
    float* __restrict__ xf)
{
    __shared__ float sf[1024];
    __shared__ float sp[8][32];
    const int t = threadIdx.x;
    const int gb = blockIdx.x;
    *(float4*)&sf[t * 4] = *(const float4*)(f3 + (size_t)gb * 1024 + t * 4);
    __syncthreads();
    const int c = t & 31, part = t >> 5;
    float acc = 0.f;
    for (int k = part * 128; k < part * 128 + 128; k++) acc += sf[k] * W[k * 32 + c];
    sp[part][c] = acc;
    __syncthreads();
    if (t < 32) {
        float v = bb[t];
#pragma unroll
        for (int p = 0; p < 8; p++) v += sp[p][t];
        float s = v, s2 = v * v;
#pragma unroll
        for (int off = 16; off >= 1; off >>= 1) {
            s += __shfl_xor(s, off);
            s2 += __shfl_xor(s2, off);
        }
        const float mu = s * (1.0f / 32.0f);
        const float var = s2 * (1.0f / 32.0f) - mu * mu;
        float y = (v - mu) * rsqrtf(var + 1e-5f) * g[t] + b[t];
        xf[gb * 32 + t] = (y >= 0.f) ? y : 0.01f * y;
    }
}

// out[b,o] = cat(gsum/cnt, xf, one_hot) @ out_W + out_b
__global__ __launch_bounds__(128) void final_out(
    const float* __restrict__ gsum, const float* __restrict__ gcnt,
    const float* __restrict__ xf, const float* __restrict__ onehot,
    const float* __restrict__ Wo, const float* __restrict__ bo,
    float* __restrict__ out)
{
    const int t = threadIdx.x;
    const int gb = t >> 1, o = t & 1;
    float cnt = gcnt[gb];
    cnt = (cnt > 1.f) ? cnt : 1.f;
    float acc = bo[o];
#pragma unroll
    for (int j = 0; j < 4; j++)  acc += (gsum[gb * 4 + j] / cnt) * Wo[j * 2 + o];
#pragma unroll
    for (int j = 0; j < 32; j++) acc += xf[gb * 32 + j] * Wo[(4 + j) * 2 + o];
#pragma unroll
    for (int j = 0; j < 20; j++) acc += onehot[gb * 20 + j] * Wo[(36 + j) * 2 + o];
    out[t] = acc;
}

extern "C" void kernel_launch(void* const* d_in, const int* in_sizes, int n_in,
                              void* d_out, int out_size, void* d_ws, size_t ws_size,
                              hipStream_t stream)
{
    const float* x        = (const float*)d_in[0];
    const int*   ei       = (const int*)d_in[1];
    const int*   batch    = (const int*)d_in[2];
    const float* features = (const float*)d_in[3];
    const float* one_hot  = (const float*)d_in[4];
    const float* W_l   = (const float*)d_in[5];
    const float* b_l   = (const float*)d_in[6];
    const float* W_r   = (const float*)d_in[7];
    const float* b_r   = (const float*)d_in[8];
    const float* att   = (const float*)d_in[9];
    const float* conv_b = (const float*)d_in[10];
    const float* jk_W  = (const float*)d_in[11];
    const float* jk_b  = (const float*)d_in[12];
    const float* l1_W  = (const float*)d_in[13];
    const float* l1_b  = (const float*)d_in[14];
    const float* ln1_g = (const float*)d_in[15];
    const float* ln1_b = (const float*)d_in[16];
    const float* l2_W  = (const float*)d_in[17];
    const float* l2_b  = (const float*)d_in[18];
    const float* ln2_g = (const float*)d_in[19];
    const float* ln2_b = (const float*)d_in[20];
    const float* l3_W  = (const float*)d_in[21];
    const float* l3_b  = (const float*)d_in[22];
    const float* ln3_g = (const float*)d_in[23];
    const float* ln3_b = (const float*)d_in[24];
    const float* fl_W  = (const float*)d_in[25];
    const float* fl_b  = (const float*)d_in[26];
    const float* ln4_g = (const float*)d_in[27];
    const float* ln4_b = (const float*)d_in[28];
    const float* out_W = (const float*)d_in[29];
    const float* out_b = (const float*)d_in[30];
    (void)in_sizes; (void)n_in; (void)out_size;

    float* ws = (float*)d_ws;
    unsigned short* xlb = (unsigned short*)(ws + 0);
    float* xr   = ws + 800000;
    unsigned short* w1t = (unsigned short*)(ws + 2400000);
    unsigned short* w2t = (unsigned short*)(ws + 2727680);
    float* gsum   = ws + 2735872;
    float* gcnt   = ws + 2736128;
    int*   cursor = (int*)(ws + 2736192);          // [782]
    int* pairs = (int*)(ws + 2737024);             // 782*8960 = 7,006,720 ints

    // fused path needs f1..xf AFTER pairs (53.9 MB total); else fall back to
    // the serial schedule with mlp scratch aliased over pairs (39 MB).
    const bool fuse = ws_size >= (size_t)13481344 * 4;
    float* f1;  unsigned short* f1b;  float* f2;  float* f3;  float* xf;
    if (fuse) {
        f1  = ws + 9743744;                        // 8192*256 f32
        f1b = (unsigned short*)(ws + 11840896);    // 8192*256 bf16
        f2  = ws + 12889472;                       // 8192*64
        f3  = ws + 13413760;                       // 8192*8
        xf  = ws + 13479296;                       // 64*32
    } else {
        f1  = ws + 2737024;
        f1b = (unsigned short*)(ws + 4834176);
        f2  = ws + 5358464;
        f3  = ws + 5882752;
        xf  = ws + 5948288;
    }

    // zero gsum+gcnt+cursor (contiguous 1102 dwords)
    hipMemsetAsync(gsum, 0, 1102 * sizeof(float), stream);

    // w1t must be ready before the gemm role (castT is a ~4 us kernel)
    castT<<<dim3(10, 256), 256, 0, stream>>>(l1_W, w1t, FEAT, 256);
    castT<<<dim3(1, 64), 256, 0, stream>>>(l2_W, w2t, 256, 64);

    if (fuse) {
        // fused: edge_bucket (512) || gemm_l1 (256) || node_xform (768)
        fused_front<<<EBLK + GEMMB + NXB, 256, 0, stream>>>(
            x, W_l, b_l, W_r, b_r, xlb, xr,
            ei, cursor, pairs,
            features, w1t, l1_b, f1);
        bucket_reduce<<<NBK, 256, 0, stream>>>(pairs, cursor, xlb, xr, att,
                                               conv_b, jk_W, jk_b, batch,
                                               gsum, gcnt);
    } else {
        node_xform<<<N_NODES / 16, 256, 0, stream>>>(x, W_l, b_l, W_r, b_r,
                                                     xlb, xr);
        edge_bucket<<<EBLK, 256, 0, stream>>>(ei, cursor, pairs);
        bucket_reduce<<<NBK, 256, 0, stream>>>(pairs, cursor, xlb, xr, att,
                                               conv_b, jk_W, jk_b, batch,
                                               gsum, gcnt);
        mfma_gemm_l1<<<dim3(MROWS / 64, 2), 256, 0, stream>>>(
            features, w1t, l1_b, f1);
    }

    ln_leaky_c256<<<MROWS, 256, 0, stream>>>(f1, f1b, ln1_g, ln1_b);
    mfma_gemm_l2<<<dim3(MROWS / 32, 1), 256, 0, stream>>>(
        f1b, w2t, l2_b, f2, MROWS, 64, 256);
    ln_leaky_c64<<<MROWS / 4, 256, 0, stream>>>(f2, ln2_g, ln2_b);
    l3_ln_leaky<<<MROWS / 32, 256, 0, stream>>>(f2, l3_W, l3_b, ln3_g, ln3_b, f3);
    flat_ln_leaky<<<NB, 256, 0, stream>>>(f3, fl_W, fl_b, ln4_g, ln4_b, xf);
    final_out<<<1, 128, 0, stream>>>(gsum, gcnt, xf, one_hot, out_W, out_b, (float*)d_out);
}